// Round 1
// baseline (155.031 us; speedup 1.0000x reference)
//
#include <hip/hip_runtime.h>
#include <stdint.h>

#define BN 4096
#define DK 512
#define THRESH 0.5f
#define MARGIN 0.1f

typedef __attribute__((ext_vector_type(8))) __bf16 bf16x8;
typedef __attribute__((ext_vector_type(4))) float f32x4;

// order-preserving float<->uint mapping for atomic min/max
__device__ __forceinline__ unsigned f2o(float f) {
    unsigned u = __float_as_uint(f);
    return (u & 0x80000000u) ? ~u : (u | 0x80000000u);
}
__device__ __forceinline__ float o2f(unsigned u) {
    unsigned v = (u & 0x80000000u) ? (u & 0x7FFFFFFFu) : ~u;
    return __uint_as_float(v);
}

__device__ __forceinline__ unsigned short f2bf(float f) {
    unsigned u = __float_as_uint(f);
    u += 0x7FFFu + ((u >> 16) & 1u);   // RNE
    return (unsigned short)(u >> 16);
}

__device__ __forceinline__ void async_cp16(void* lds, const void* g) {
    __builtin_amdgcn_global_load_lds(
        (const __attribute__((address_space(1))) void*)g,
        (__attribute__((address_space(3))) void*)lds,
        16, 0, 0);
}

__global__ void cvt_kernel(const float4* __restrict__ in, ushort4* __restrict__ out) {
    int i = blockIdx.x * blockDim.x + threadIdx.x;   // 524288 threads, 4 elems each
    float4 v = in[i];
    ushort4 o;
    o.x = f2bf(v.x); o.y = f2bf(v.y); o.z = f2bf(v.z); o.w = f2bf(v.w);
    out[i] = o;
}

// PHASE 0: per-row min over positives / max over negatives  (ordered-uint atomics)
// PHASE 1: per-row masked exp-sums using thresholds from phase 0
template <int PHASE>
__global__ __launch_bounds__(256, 2) void ms_pass(
    const unsigned short* __restrict__ Fb,   // bf16 bits [4096][512] row-major
    const int* __restrict__ labels,
    unsigned* __restrict__ minpos_u,
    unsigned* __restrict__ maxneg_u,
    float* __restrict__ pos_sum,
    float* __restrict__ neg_sum)
{
    __shared__ __align__(16) unsigned short As[128 * 64];  // [row][k] rows of tile
    __shared__ __align__(16) unsigned short Bs[128 * 64];  // [col][k]
    __shared__ int labR[128];
    __shared__ int labC[128];
    __shared__ float thrP[128];
    __shared__ float thrN[128];

    const int t    = threadIdx.x;
    const int lane = t & 63;
    const int w    = t >> 6;
    const int wr   = w >> 1, wc = w & 1;
    const int quad = lane >> 4;
    const int cIdx = lane & 15;

    const int rowBase = blockIdx.y * 128;
    const int colBase = blockIdx.x * 128;

    if (t < 128) {
        labR[t] = labels[rowBase + t];
        if (PHASE == 1) {
            unsigned up = minpos_u[rowBase + t];
            thrP[t] = (up == 0xFFFFFFFFu) ? 0.2f : o2f(up);   // pos_thr fallback 0.2
            unsigned un = maxneg_u[rowBase + t];
            thrN[t] = (un == 0u) ? 0.8f : o2f(un);            // neg_thr fallback 0.8
        }
    } else {
        labC[t - 128] = labels[colBase + (t - 128)];
    }

    f32x4 acc[4][4];
#pragma unroll
    for (int i = 0; i < 4; ++i)
#pragma unroll
        for (int j = 0; j < 4; ++j) acc[i][j] = (f32x4){0.f, 0.f, 0.f, 0.f};

    const int lrow   = t >> 3;   // 0..31 (row within a 32-row staging slab)
    const int lcol   = t & 7;    // which 16B chunk of the 64-elem k-slice
    const int ldsOff = t * 8;    // elements; lane-contiguous: base + lane*16B

    for (int k0 = 0; k0 < DK; k0 += 64) {
#pragma unroll
        for (int it = 0; it < 4; ++it) {
            const unsigned short* gA =
                Fb + (size_t)(rowBase + it * 32 + lrow) * DK + k0 + lcol * 8;
            async_cp16(&As[it * 2048 + ldsOff], gA);
        }
#pragma unroll
        for (int it = 0; it < 4; ++it) {
            const unsigned short* gB =
                Fb + (size_t)(colBase + it * 32 + lrow) * DK + k0 + lcol * 8;
            async_cp16(&Bs[it * 2048 + ldsOff], gB);
        }
        __syncthreads();   // compiler drains vmcnt before s_barrier

#pragma unroll
        for (int kk = 0; kk < 2; ++kk) {
            bf16x8 af[4], bg[4];
#pragma unroll
            for (int im = 0; im < 4; ++im) {
                int r = wr * 64 + im * 16 + cIdx;           // A[m=lane&15][k=quad*8+j]
                af[im] = *reinterpret_cast<const bf16x8*>(&As[r * 64 + kk * 32 + quad * 8]);
            }
#pragma unroll
            for (int jn = 0; jn < 4; ++jn) {
                int c = wc * 64 + jn * 16 + cIdx;           // B[k=quad*8+j][n=lane&15]
                bg[jn] = *reinterpret_cast<const bf16x8*>(&Bs[c * 64 + kk * 32 + quad * 8]);
            }
#pragma unroll
            for (int im = 0; im < 4; ++im)
#pragma unroll
                for (int jn = 0; jn < 4; ++jn)
                    acc[im][jn] = __builtin_amdgcn_mfma_f32_16x16x32_bf16(
                        af[im], bg[jn], acc[im][jn], 0, 0, 0);
        }
        __syncthreads();
    }

    // Epilogue. C/D layout (16x16): col = lane&15, row = quad*4 + reg.
    // All 16 lanes of a quad share the same row set -> quad-local shfl reduce.
#pragma unroll
    for (int im = 0; im < 4; ++im) {
#pragma unroll
        for (int rg = 0; rg < 4; ++rg) {
            const int rloc = wr * 64 + im * 16 + quad * 4 + rg;
            const int grow = rowBase + rloc;
            const int lr   = labR[rloc];
            if (PHASE == 0) {
                float mn = INFINITY, mx = -INFINITY;
#pragma unroll
                for (int jn = 0; jn < 4; ++jn) {
                    const int cloc = wc * 64 + jn * 16 + cIdx;
                    const int gcol = colBase + cloc;
                    const float s  = acc[im][jn][rg];
                    const bool same = (lr == labC[cloc]);
                    if (same && (grow != gcol)) mn = fminf(mn, s);
                    if (!same) mx = fmaxf(mx, s);
                }
#pragma unroll
                for (int off = 1; off < 16; off <<= 1) {
                    mn = fminf(mn, __shfl_xor(mn, off, 64));
                    mx = fmaxf(mx, __shfl_xor(mx, off, 64));
                }
                if (cIdx == 0) {
                    if (mn < 1e30f)  atomicMin(&minpos_u[grow], f2o(mn));
                    if (mx > -1e30f) atomicMax(&maxneg_u[grow], f2o(mx));
                }
            } else {
                const float tP = thrP[rloc];
                const float tN = thrN[rloc];
                float ps = 0.f, ns = 0.f;
#pragma unroll
                for (int jn = 0; jn < 4; ++jn) {
                    const int cloc = wc * 64 + jn * 16 + cIdx;
                    const int gcol = colBase + cloc;
                    const float s  = acc[im][jn][rg];
                    const bool same = (lr == labC[cloc]);
                    if (same && (grow != gcol) && (s - MARGIN < tN))
                        ps += __expf(-2.0f * (s - THRESH));
                    if ((!same) && (s + MARGIN > tP))
                        ns += __expf(40.0f * (s - THRESH));
                }
#pragma unroll
                for (int off = 1; off < 16; off <<= 1) {
                    ps += __shfl_xor(ps, off, 64);
                    ns += __shfl_xor(ns, off, 64);
                }
                if (cIdx == 0) {
                    if (ps != 0.f) atomicAdd(&pos_sum[grow], ps);
                    if (ns != 0.f) atomicAdd(&neg_sum[grow], ns);
                }
            }
        }
    }
}

__global__ void finalize_kernel(const float* __restrict__ pos_sum,
                                const float* __restrict__ neg_sum,
                                const int* __restrict__ label_num,
                                float* __restrict__ out)
{
    __shared__ float red[8];
    const int t   = threadIdx.x;   // 512 threads, single block
    const int lim = BN - label_num[0];
    float local = 0.f;
    for (int i = t; i < BN; i += 512) {
        float ps = pos_sum[i], ns = neg_sum[i];
        // exp terms are strictly positive -> sum>0 <=> any() of the mined mask
        if (ps > 0.f && ns > 0.f && i < lim)
            local += 0.5f * log1pf(ps) + 0.025f * log1pf(ns);
    }
#pragma unroll
    for (int off = 1; off < 64; off <<= 1) local += __shfl_xor(local, off, 64);
    if ((t & 63) == 0) red[t >> 6] = local;
    __syncthreads();
    if (t == 0) {
        float s = 0.f;
        for (int i = 0; i < 8; ++i) s += red[i];
        out[0] = s / (float)BN;
    }
}

extern "C" void kernel_launch(void* const* d_in, const int* in_sizes, int n_in,
                              void* d_out, int out_size, void* d_ws, size_t ws_size,
                              hipStream_t stream)
{
    const float* feats     = (const float*)d_in[0];
    const int*   labels    = (const int*)d_in[1];
    const int*   label_num = (const int*)d_in[2];
    float*       out       = (float*)d_out;

    char* ws = (char*)d_ws;
    unsigned short* Fb    = (unsigned short*)ws;              // 4 MB bf16 feats
    unsigned* minpos_u    = (unsigned*)(ws + 4u * 1024u * 1024u);
    unsigned* maxneg_u    = minpos_u + BN;
    float*    pos_sum     = (float*)(maxneg_u + BN);
    float*    neg_sum     = pos_sum + BN;

    // min init = all-ones ordered-uint (= +inf sentinel); max/sums init = 0
    hipMemsetAsync(minpos_u, 0xFF, BN * sizeof(unsigned), stream);
    hipMemsetAsync(maxneg_u, 0x00, BN * sizeof(unsigned) * 3, stream);

    cvt_kernel<<<2048, 256, 0, stream>>>((const float4*)feats, (ushort4*)Fb);

    dim3 grid(BN / 128, BN / 128);   // 32 x 32 = 1024 workgroups
    ms_pass<0><<<grid, 256, 0, stream>>>(Fb, labels, minpos_u, maxneg_u, pos_sum, neg_sum);
    ms_pass<1><<<grid, 256, 0, stream>>>(Fb, labels, minpos_u, maxneg_u, pos_sum, neg_sum);

    finalize_kernel<<<1, 512, 0, stream>>>(pos_sum, neg_sum, label_num, out);
}

// Round 2
// 131.252 us; speedup vs baseline: 1.1812x; 1.1812x over previous
//
#include <hip/hip_runtime.h>
#include <stdint.h>

#define BN 4096
#define DK 512
#define THRESH 0.5f
#define MARGIN 0.1f

typedef __attribute__((ext_vector_type(8))) __bf16 bf16x8;
typedef __attribute__((ext_vector_type(4))) float f32x4;

// order-preserving float<->uint mapping for atomic min/max
__device__ __forceinline__ unsigned f2o(float f) {
    unsigned u = __float_as_uint(f);
    return (u & 0x80000000u) ? ~u : (u | 0x80000000u);
}
__device__ __forceinline__ float o2f(unsigned u) {
    unsigned v = (u & 0x80000000u) ? (u & 0x7FFFFFFFu) : ~u;
    return __uint_as_float(v);
}

__device__ __forceinline__ unsigned short f2bf(float f) {
    unsigned u = __float_as_uint(f);
    u += 0x7FFFu + ((u >> 16) & 1u);   // RNE
    return (unsigned short)(u >> 16);
}

__device__ __forceinline__ void async_cp16(void* lds, const void* g) {
    __builtin_amdgcn_global_load_lds(
        (const __attribute__((address_space(1))) void*)g,
        (__attribute__((address_space(3))) void*)lds,
        16, 0, 0);
}

// converts feats -> bf16; block 0 also initializes the reduction arrays
// (replaces two hipMemsetAsync dispatches)
__global__ void cvt_kernel(const float4* __restrict__ in, ushort4* __restrict__ out,
                           unsigned* __restrict__ minpos_u, unsigned* __restrict__ maxneg_u,
                           float* __restrict__ pos_sum, float* __restrict__ neg_sum) {
    int i = blockIdx.x * blockDim.x + threadIdx.x;   // 524288 threads, 4 elems each
    float4 v = in[i];
    ushort4 o;
    o.x = f2bf(v.x); o.y = f2bf(v.y); o.z = f2bf(v.z); o.w = f2bf(v.w);
    out[i] = o;
    if (blockIdx.x == 0) {
        for (int j = threadIdx.x; j < BN; j += 256) {
            minpos_u[j] = 0xFFFFFFFFu;   // ordered-uint +inf sentinel
            maxneg_u[j] = 0u;            // ordered-uint -inf sentinel
            pos_sum[j]  = 0.f;
            neg_sum[j]  = 0.f;
        }
    }
}

// PHASE 0: per-row min over positives / max over negatives  (ordered-uint atomics)
// PHASE 1: per-row masked exp-sums using thresholds from phase 0
//
// LDS layout is XOR-swizzled: slot p of row r holds global 16B-chunk (p ^ (r&7)).
// global_load_lds pins the LDS dest to lane-contiguous, so the swizzle is applied
// on the GLOBAL gather side (stays within one 128B segment -> still coalesced).
// This spreads the MFMA fragment reads (stride 128B between lanes, which would
// alias all 16 lanes of a quad onto one 4-bank group) across all 32 banks.
template <int PHASE>
__global__ __launch_bounds__(256, 4) void ms_pass(
    const unsigned short* __restrict__ Fb,   // bf16 bits [4096][512] row-major
    const int* __restrict__ labels,
    unsigned* __restrict__ minpos_u,
    unsigned* __restrict__ maxneg_u,
    float* __restrict__ pos_sum,
    float* __restrict__ neg_sum)
{
    __shared__ __align__(16) unsigned short As[128 * 64];  // [row][k] swizzled
    __shared__ __align__(16) unsigned short Bs[128 * 64];  // [col][k] swizzled
    __shared__ int labR[128];
    __shared__ int labC[128];
    __shared__ float thrP[128];
    __shared__ float thrN[128];

    const int t    = threadIdx.x;
    const int lane = t & 63;
    const int w    = t >> 6;
    const int wr   = w >> 1, wc = w & 1;
    const int quad = lane >> 4;
    const int cIdx = lane & 15;

    const int rowBase = blockIdx.y * 128;
    const int colBase = blockIdx.x * 128;

    if (t < 128) {
        labR[t] = labels[rowBase + t];
        if (PHASE == 1) {
            unsigned up = minpos_u[rowBase + t];
            thrP[t] = (up == 0xFFFFFFFFu) ? 0.2f : o2f(up);   // pos_thr fallback 0.2
            unsigned un = maxneg_u[rowBase + t];
            thrN[t] = (un == 0u) ? 0.8f : o2f(un);            // neg_thr fallback 0.8
        }
    } else {
        labC[t - 128] = labels[colBase + (t - 128)];
    }

    f32x4 acc[4][4];
#pragma unroll
    for (int i = 0; i < 4; ++i)
#pragma unroll
        for (int j = 0; j < 4; ++j) acc[i][j] = (f32x4){0.f, 0.f, 0.f, 0.f};

    const int lrow   = t >> 3;               // 0..31 (row within a 32-row staging slab)
    const int swz    = (t & 7) ^ (lrow & 7); // global chunk this lane fetches (XOR swizzle)
    const int ldsOff = t * 8;                // elements; lane-contiguous LDS dest

    for (int k0 = 0; k0 < DK; k0 += 64) {
#pragma unroll
        for (int it = 0; it < 4; ++it) {
            const unsigned short* gA =
                Fb + (size_t)(rowBase + it * 32 + lrow) * DK + k0 + swz * 8;
            async_cp16(&As[it * 2048 + ldsOff], gA);
        }
#pragma unroll
        for (int it = 0; it < 4; ++it) {
            const unsigned short* gB =
                Fb + (size_t)(colBase + it * 32 + lrow) * DK + k0 + swz * 8;
            async_cp16(&Bs[it * 2048 + ldsOff], gB);
        }
        __syncthreads();   // compiler drains vmcnt before s_barrier

#pragma unroll
        for (int kk = 0; kk < 2; ++kk) {
            bf16x8 af[4], bg[4];
#pragma unroll
            for (int im = 0; im < 4; ++im) {
                int r = wr * 64 + im * 16 + cIdx;     // A[m=lane&15][k=quad*8+j]
                int p = (kk * 4 + quad) ^ (r & 7);    // de-swizzle chunk index
                af[im] = *reinterpret_cast<const bf16x8*>(&As[r * 64 + p * 8]);
            }
#pragma unroll
            for (int jn = 0; jn < 4; ++jn) {
                int c = wc * 64 + jn * 16 + cIdx;     // B[k=quad*8+j][n=lane&15]
                int p = (kk * 4 + quad) ^ (c & 7);
                bg[jn] = *reinterpret_cast<const bf16x8*>(&Bs[c * 64 + p * 8]);
            }
#pragma unroll
            for (int im = 0; im < 4; ++im)
#pragma unroll
                for (int jn = 0; jn < 4; ++jn)
                    acc[im][jn] = __builtin_amdgcn_mfma_f32_16x16x32_bf16(
                        af[im], bg[jn], acc[im][jn], 0, 0, 0);
        }
        __syncthreads();
    }

    // Epilogue. C/D layout (16x16): col = lane&15, row = quad*4 + reg.
    // All 16 lanes of a quad share the same row set -> quad-local shfl reduce.
#pragma unroll
    for (int im = 0; im < 4; ++im) {
#pragma unroll
        for (int rg = 0; rg < 4; ++rg) {
            const int rloc = wr * 64 + im * 16 + quad * 4 + rg;
            const int grow = rowBase + rloc;
            const int lr   = labR[rloc];
            if (PHASE == 0) {
                float mn = INFINITY, mx = -INFINITY;
#pragma unroll
                for (int jn = 0; jn < 4; ++jn) {
                    const int cloc = wc * 64 + jn * 16 + cIdx;
                    const int gcol = colBase + cloc;
                    const float s  = acc[im][jn][rg];
                    const bool same = (lr == labC[cloc]);
                    if (same && (grow != gcol)) mn = fminf(mn, s);
                    if (!same) mx = fmaxf(mx, s);
                }
#pragma unroll
                for (int off = 1; off < 16; off <<= 1) {
                    mn = fminf(mn, __shfl_xor(mn, off, 64));
                    mx = fmaxf(mx, __shfl_xor(mx, off, 64));
                }
                if (cIdx == 0) {
                    if (mn < 1e30f)  atomicMin(&minpos_u[grow], f2o(mn));
                    if (mx > -1e30f) atomicMax(&maxneg_u[grow], f2o(mx));
                }
            } else {
                const float tP = thrP[rloc];
                const float tN = thrN[rloc];
                float ps = 0.f, ns = 0.f;
#pragma unroll
                for (int jn = 0; jn < 4; ++jn) {
                    const int cloc = wc * 64 + jn * 16 + cIdx;
                    const int gcol = colBase + cloc;
                    const float s  = acc[im][jn][rg];
                    const bool same = (lr == labC[cloc]);
                    if (same && (grow != gcol) && (s - MARGIN < tN))
                        ps += __expf(-2.0f * (s - THRESH));
                    if ((!same) && (s + MARGIN > tP))
                        ns += __expf(40.0f * (s - THRESH));
                }
#pragma unroll
                for (int off = 1; off < 16; off <<= 1) {
                    ps += __shfl_xor(ps, off, 64);
                    ns += __shfl_xor(ns, off, 64);
                }
                if (cIdx == 0) {
                    if (ps != 0.f) atomicAdd(&pos_sum[grow], ps);
                    if (ns != 0.f) atomicAdd(&neg_sum[grow], ns);
                }
            }
        }
    }
}

__global__ void finalize_kernel(const float* __restrict__ pos_sum,
                                const float* __restrict__ neg_sum,
                                const int* __restrict__ label_num,
                                float* __restrict__ out)
{
    __shared__ float red[8];
    const int t   = threadIdx.x;   // 512 threads, single block
    const int lim = BN - label_num[0];
    float local = 0.f;
    for (int i = t; i < BN; i += 512) {
        float ps = pos_sum[i], ns = neg_sum[i];
        // exp terms are strictly positive -> sum>0 <=> any() of the mined mask
        if (ps > 0.f && ns > 0.f && i < lim)
            local += 0.5f * log1pf(ps) + 0.025f * log1pf(ns);
    }
#pragma unroll
    for (int off = 1; off < 64; off <<= 1) local += __shfl_xor(local, off, 64);
    if ((t & 63) == 0) red[t >> 6] = local;
    __syncthreads();
    if (t == 0) {
        float s = 0.f;
        for (int i = 0; i < 8; ++i) s += red[i];
        out[0] = s / (float)BN;
    }
}

extern "C" void kernel_launch(void* const* d_in, const int* in_sizes, int n_in,
                              void* d_out, int out_size, void* d_ws, size_t ws_size,
                              hipStream_t stream)
{
    const float* feats     = (const float*)d_in[0];
    const int*   labels    = (const int*)d_in[1];
    const int*   label_num = (const int*)d_in[2];
    float*       out       = (float*)d_out;

    char* ws = (char*)d_ws;
    unsigned short* Fb    = (unsigned short*)ws;              // 4 MB bf16 feats
    unsigned* minpos_u    = (unsigned*)(ws + 4u * 1024u * 1024u);
    unsigned* maxneg_u    = minpos_u + BN;
    float*    pos_sum     = (float*)(maxneg_u + BN);
    float*    neg_sum     = pos_sum + BN;

    cvt_kernel<<<2048, 256, 0, stream>>>((const float4*)feats, (ushort4*)Fb,
                                         minpos_u, maxneg_u, pos_sum, neg_sum);

    dim3 grid(BN / 128, BN / 128);   // 32 x 32 = 1024 workgroups
    ms_pass<0><<<grid, 256, 0, stream>>>(Fb, labels, minpos_u, maxneg_u, pos_sum, neg_sum);
    ms_pass<1><<<grid, 256, 0, stream>>>(Fb, labels, minpos_u, maxneg_u, pos_sum, neg_sum);

    finalize_kernel<<<1, 512, 0, stream>>>(pos_sum, neg_sum, label_num, out);
}

// Round 4
// 124.685 us; speedup vs baseline: 1.2434x; 1.0527x over previous
//
#include <hip/hip_runtime.h>
#include <stdint.h>

#define BN 4096
#define DK 512
#define THRESH 0.5f
#define MARGIN 0.1f

typedef __attribute__((ext_vector_type(8))) __bf16 bf16x8;
typedef __attribute__((ext_vector_type(4))) float f32x4;
typedef __attribute__((ext_vector_type(8))) unsigned short ushort8;

__device__ __forceinline__ unsigned short f2bf(float f) {
    unsigned u = __float_as_uint(f);
    u += 0x7FFFu + ((u >> 16) & 1u);   // RNE
    return (unsigned short)(u >> 16);
}
__device__ __forceinline__ float bf2f(unsigned short b) {
    return __uint_as_float((unsigned)b << 16);
}

__device__ __forceinline__ void async_cp16(void* lds, const void* g) {
    __builtin_amdgcn_global_load_lds(
        (const __attribute__((address_space(1))) void*)g,
        (__attribute__((address_space(3))) void*)lds,
        16, 0, 0);
}

// feats fp32 -> bf16 (for MFMA); block 0 thread 0 zero-inits out[0]
// (harness re-poisons d_out to 0xAA before every timed replay).
__global__ void cvt_kernel(const float4* __restrict__ in, ushort4* __restrict__ out,
                           float* __restrict__ loss_out) {
    int i = blockIdx.x * blockDim.x + threadIdx.x;   // 524288 threads, 4 elems each
    float4 v = in[i];
    ushort4 o;
    o.x = f2bf(v.x); o.y = f2bf(v.y); o.z = f2bf(v.z); o.w = f2bf(v.w);
    out[i] = o;
    if (blockIdx.x == 0 && threadIdx.x == 0) loss_out[0] = 0.f;
}

// Pure GEMM: sim = Fb @ Fb^T for one 128x128 tile; store sim as bf16.
// LDS staging XOR-swizzled on the global-gather side (round-2 bank-conflict
// fix: fragment reads have 128B lane stride, which would alias a quad's 16
// lanes onto one 4-bank group; the swizzle spreads them across all 32 banks
// while keeping the global gather inside one 128B segment -> coalesced).
__global__ __launch_bounds__(256, 4) void ms_gemm(
    const unsigned short* __restrict__ Fb,   // bf16 bits [4096][512] row-major
    unsigned short* __restrict__ simb)       // bf16 bits [4096][4096]
{
    __shared__ __align__(16) unsigned short As[128 * 64];  // [row][k] swizzled
    __shared__ __align__(16) unsigned short Bs[128 * 64];  // [col][k] swizzled

    const int t    = threadIdx.x;
    const int lane = t & 63;
    const int w    = t >> 6;
    const int wr   = w >> 1, wc = w & 1;
    const int quad = lane >> 4;
    const int cIdx = lane & 15;

    const int rowBase = blockIdx.y * 128;
    const int colBase = blockIdx.x * 128;

    f32x4 acc[4][4];
#pragma unroll
    for (int i = 0; i < 4; ++i)
#pragma unroll
        for (int j = 0; j < 4; ++j) acc[i][j] = (f32x4){0.f, 0.f, 0.f, 0.f};

    const int lrow   = t >> 3;               // 0..31 (row within a 32-row staging slab)
    const int swz    = (t & 7) ^ (lrow & 7); // XOR-swizzled chunk this lane fetches
    const int ldsOff = t * 8;                // lane-contiguous LDS dest (HW requirement)

    for (int k0 = 0; k0 < DK; k0 += 64) {
#pragma unroll
        for (int it = 0; it < 4; ++it) {
            const unsigned short* gA =
                Fb + (size_t)(rowBase + it * 32 + lrow) * DK + k0 + swz * 8;
            async_cp16(&As[it * 2048 + ldsOff], gA);
        }
#pragma unroll
        for (int it = 0; it < 4; ++it) {
            const unsigned short* gB =
                Fb + (size_t)(colBase + it * 32 + lrow) * DK + k0 + swz * 8;
            async_cp16(&Bs[it * 2048 + ldsOff], gB);
        }
        __syncthreads();   // compiler drains vmcnt before s_barrier

#pragma unroll
        for (int kk = 0; kk < 2; ++kk) {
            bf16x8 af[4], bg[4];
#pragma unroll
            for (int im = 0; im < 4; ++im) {
                int r = wr * 64 + im * 16 + cIdx;     // A[m=lane&15][k=quad*8+j]
                int p = (kk * 4 + quad) ^ (r & 7);    // de-swizzle chunk index
                af[im] = *reinterpret_cast<const bf16x8*>(&As[r * 64 + p * 8]);
            }
#pragma unroll
            for (int jn = 0; jn < 4; ++jn) {
                int c = wc * 64 + jn * 16 + cIdx;     // B[k=quad*8+j][n=lane&15]
                int p = (kk * 4 + quad) ^ (c & 7);
                bg[jn] = *reinterpret_cast<const bf16x8*>(&Bs[c * 64 + p * 8]);
            }
#pragma unroll
            for (int im = 0; im < 4; ++im)
#pragma unroll
                for (int jn = 0; jn < 4; ++jn)
                    acc[im][jn] = __builtin_amdgcn_mfma_f32_16x16x32_bf16(
                        af[im], bg[jn], acc[im][jn], 0, 0, 0);
        }
        __syncthreads();
    }

    // Epilogue: store bf16 sim. C/D layout (16x16): col=lane&15, row=quad*4+reg.
    // 16 consecutive cIdx lanes write 16 consecutive ushorts -> coalesced 32B.
#pragma unroll
    for (int im = 0; im < 4; ++im)
#pragma unroll
        for (int rg = 0; rg < 4; ++rg) {
            const int grow = rowBase + wr * 64 + im * 16 + quad * 4 + rg;
            unsigned short* dst = simb + (size_t)grow * BN + colBase + wc * 64 + cIdx;
#pragma unroll
            for (int jn = 0; jn < 4; ++jn)
                dst[jn * 16] = f2bf(acc[im][jn][rg]);
        }
}

// Per-row pass: one wave owns one full row (held in 32 VGPRs), so the row's
// min/max thresholds are wave-local -- no global atomics or threshold round
// trip. 256 blocks x 4 waves x 4 rows. Block-sums the per-row contributions
// and does ONE atomicAdd(out) per block (pre-scaled by 1/BN).
__global__ __launch_bounds__(256) void ms_rows(
    const unsigned short* __restrict__ simb,
    const int* __restrict__ labels,
    const int* __restrict__ label_num,
    float* __restrict__ out)
{
    __shared__ int   labS[BN];   // 16 KB
    __shared__ float bsum[4];

    const int t    = threadIdx.x;
    const int lane = t & 63;
    const int w    = t >> 6;

    for (int i = t; i < BN; i += 256) labS[i] = labels[i];
    __syncthreads();

    const int lim = BN - label_num[0];
    float wsum = 0.f;

    for (int rr = 0; rr < 4; ++rr) {
        const int row = blockIdx.x * 16 + w * 4 + rr;
        const int lr  = labS[row];
        const ushort8* rp = (const ushort8*)(simb + (size_t)row * BN);

        ushort8 d[8];
        uint64_t mpos = 0, msame = 0;
        float mn = INFINITY, mx = -INFINITY;
#pragma unroll
        for (int j = 0; j < 8; ++j) {
            d[j] = rp[j * 64 + lane];
#pragma unroll
            for (int e = 0; e < 8; ++e) {
                const int col = (j * 64 + lane) * 8 + e;
                const float s = bf2f(d[j][e]);
                const bool same = (labS[col] == lr);
                const bool pos  = same && (col != row);
                if (pos)   mn = fminf(mn, s);
                if (!same) mx = fmaxf(mx, s);
                msame |= (uint64_t)same << (j * 8 + e);
                mpos  |= (uint64_t)pos  << (j * 8 + e);
            }
        }
#pragma unroll
        for (int off = 1; off < 64; off <<= 1) {
            mn = fminf(mn, __shfl_xor(mn, off, 64));
            mx = fmaxf(mx, __shfl_xor(mx, off, 64));
        }
        const float tP = (mn < 1e30f)  ? mn : 0.2f;   // pos_thr fallback
        const float tN = (mx > -1e30f) ? mx : 0.8f;   // neg_thr fallback

        float ps = 0.f, ns = 0.f;
#pragma unroll
        for (int j = 0; j < 8; ++j)
#pragma unroll
            for (int e = 0; e < 8; ++e) {
                const int k = j * 8 + e;
                const float s = bf2f(d[j][e]);
                if (((mpos >> k) & 1) && (s - MARGIN < tN))
                    ps += __expf(-2.0f * (s - THRESH));
                if (!((msame >> k) & 1) && (s + MARGIN > tP))
                    ns += __expf(40.0f * (s - THRESH));
            }
#pragma unroll
        for (int off = 1; off < 64; off <<= 1) {
            ps += __shfl_xor(ps, off, 64);
            ns += __shfl_xor(ns, off, 64);
        }
        // exp terms are strictly positive -> sum>0 <=> any() of mined mask
        if (lane == 0 && ps > 0.f && ns > 0.f && row < lim)
            wsum += 0.5f * log1pf(ps) + 0.025f * log1pf(ns);
    }

    if (lane == 0) bsum[w] = wsum;
    __syncthreads();
    if (t == 0)
        atomicAdd(out, (bsum[0] + bsum[1] + bsum[2] + bsum[3]) * (1.0f / (float)BN));
}

extern "C" void kernel_launch(void* const* d_in, const int* in_sizes, int n_in,
                              void* d_out, int out_size, void* d_ws, size_t ws_size,
                              hipStream_t stream)
{
    const float* feats     = (const float*)d_in[0];
    const int*   labels    = (const int*)d_in[1];
    const int*   label_num = (const int*)d_in[2];
    float*       out       = (float*)d_out;

    char* ws = (char*)d_ws;
    unsigned short* Fb   = (unsigned short*)ws;                       // 4 MB bf16 feats
    unsigned short* simb = (unsigned short*)(ws + 4u * 1024u * 1024u); // 32 MB bf16 sim

    cvt_kernel<<<2048, 256, 0, stream>>>((const float4*)feats, (ushort4*)Fb, out);

    dim3 grid(BN / 128, BN / 128);   // 32 x 32 = 1024 workgroups
    ms_gemm<<<grid, 256, 0, stream>>>(Fb, simb);

    ms_rows<<<256, 256, 0, stream>>>(simb, labels, label_num, out);
}

// Round 5
// 112.240 us; speedup vs baseline: 1.3813x; 1.1109x over previous
//
#include <hip/hip_runtime.h>
#include <stdint.h>

#define BN 4096
#define DK 512
#define THRESH 0.5f
#define MARGIN 0.1f

typedef __attribute__((ext_vector_type(8))) __bf16 bf16x8;
typedef __attribute__((ext_vector_type(4))) float f32x4;
typedef __attribute__((ext_vector_type(8))) unsigned short ushort8;

__device__ __forceinline__ unsigned short f2bf(float f) {
    unsigned u = __float_as_uint(f);
    u += 0x7FFFu + ((u >> 16) & 1u);   // RNE
    return (unsigned short)(u >> 16);
}
__device__ __forceinline__ float bf2f(unsigned short b) {
    return __uint_as_float((unsigned)b << 16);
}

__device__ __forceinline__ void async_cp16(void* lds, const void* g) {
    __builtin_amdgcn_global_load_lds(
        (const __attribute__((address_space(1))) void*)g,
        (__attribute__((address_space(3))) void*)lds,
        16, 0, 0);
}

// feats fp32 -> bf16 (for MFMA); block 0 thread 0 zero-inits out[0]
// (harness re-poisons d_out to 0xAA before every timed replay).
__global__ void cvt_kernel(const float4* __restrict__ in, ushort4* __restrict__ out,
                           float* __restrict__ loss_out) {
    int i = blockIdx.x * blockDim.x + threadIdx.x;   // 524288 threads, 4 elems each
    float4 v = in[i];
    ushort4 o;
    o.x = f2bf(v.x); o.y = f2bf(v.y); o.z = f2bf(v.z); o.w = f2bf(v.w);
    out[i] = o;
    if (blockIdx.x == 0 && threadIdx.x == 0) loss_out[0] = 0.f;
}

// Triangular GEMM: sim = Fb @ Fb^T. sim is symmetric and our accumulation
// order is identical for (i,j)/(j,i), so only the 528 upper-triangle 128x128
// tiles are computed; off-diagonal blocks also store C^T (mirror) via an LDS
// round-trip reusing the 32 KB staging buffer (XOR-swizzled 16B chunks so
// both LDS phases avoid bank conflicts; global stores stay 16B-coalesced).
// K-loop staging keeps the round-2 XOR swizzle on the global-gather side.
__global__ __launch_bounds__(256, 4) void ms_gemm(
    const unsigned short* __restrict__ Fb,   // bf16 bits [4096][512] row-major
    unsigned short* __restrict__ simb)       // bf16 bits [4096][4096]
{
    __shared__ __align__(16) unsigned short SMEM[2 * 128 * 64];  // As|Bs, reused as 128x128 C^T
    unsigned short* As = SMEM;            // [row][k] swizzled
    unsigned short* Bs = SMEM + 128 * 64; // [col][k] swizzled

    const int t    = threadIdx.x;
    const int lane = t & 63;
    const int w    = t >> 6;
    const int wr   = w >> 1, wc = w & 1;
    const int quad = lane >> 4;
    const int cIdx = lane & 15;

    // map linear block id -> upper-triangle tile (by <= bx), 528 blocks
    int l = blockIdx.x, by = 0;
    while (l >= 32 - by) { l -= (32 - by); ++by; }
    const int bx = by + l;
    const int rowBase = by * 128;
    const int colBase = bx * 128;

    f32x4 acc[4][4];
#pragma unroll
    for (int i = 0; i < 4; ++i)
#pragma unroll
        for (int j = 0; j < 4; ++j) acc[i][j] = (f32x4){0.f, 0.f, 0.f, 0.f};

    const int lrow   = t >> 3;               // 0..31 (row within a 32-row staging slab)
    const int swz    = (t & 7) ^ (lrow & 7); // XOR-swizzled chunk this lane fetches
    const int ldsOff = t * 8;                // lane-contiguous LDS dest (HW requirement)

    for (int k0 = 0; k0 < DK; k0 += 64) {
#pragma unroll
        for (int it = 0; it < 4; ++it) {
            const unsigned short* gA =
                Fb + (size_t)(rowBase + it * 32 + lrow) * DK + k0 + swz * 8;
            async_cp16(&As[it * 2048 + ldsOff], gA);
        }
#pragma unroll
        for (int it = 0; it < 4; ++it) {
            const unsigned short* gB =
                Fb + (size_t)(colBase + it * 32 + lrow) * DK + k0 + swz * 8;
            async_cp16(&Bs[it * 2048 + ldsOff], gB);
        }
        __syncthreads();   // compiler drains vmcnt before s_barrier

#pragma unroll
        for (int kk = 0; kk < 2; ++kk) {
            bf16x8 af[4], bg[4];
#pragma unroll
            for (int im = 0; im < 4; ++im) {
                int r = wr * 64 + im * 16 + cIdx;     // A[m=lane&15][k=quad*8+j]
                int p = (kk * 4 + quad) ^ (r & 7);    // de-swizzle chunk index
                af[im] = *reinterpret_cast<const bf16x8*>(&As[r * 64 + p * 8]);
            }
#pragma unroll
            for (int jn = 0; jn < 4; ++jn) {
                int c = wc * 64 + jn * 16 + cIdx;     // B[k=quad*8+j][n=lane&15]
                int p = (kk * 4 + quad) ^ (c & 7);
                bg[jn] = *reinterpret_cast<const bf16x8*>(&Bs[c * 64 + p * 8]);
            }
#pragma unroll
            for (int im = 0; im < 4; ++im)
#pragma unroll
                for (int jn = 0; jn < 4; ++jn)
                    acc[im][jn] = __builtin_amdgcn_mfma_f32_16x16x32_bf16(
                        af[im], bg[jn], acc[im][jn], 0, 0, 0);
        }
        __syncthreads();   // last iteration: also guards SMEM reuse below
    }

    // Direct store. C/D layout (16x16): col=lane&15, row=quad*4+reg.
#pragma unroll
    for (int im = 0; im < 4; ++im)
#pragma unroll
        for (int rg = 0; rg < 4; ++rg) {
            const int grow = rowBase + wr * 64 + im * 16 + quad * 4 + rg;
            unsigned short* dst = simb + (size_t)grow * BN + colBase + wc * 64 + cIdx;
#pragma unroll
            for (int jn = 0; jn < 4; ++jn)
                dst[jn * 16] = f2bf(acc[im][jn][rg]);
        }

    if (by == bx) return;

    // Mirror store: write C^T into SMEM (phys 8B-chunk XOR-swizzled by column),
    // then read rows of C^T and store 16B-coalesced to sim[col][row].
#pragma unroll
    for (int im = 0; im < 4; ++im)
#pragma unroll
        for (int jn = 0; jn < 4; ++jn) {
            ushort4 v;
            v.x = f2bf(acc[im][jn][0]);
            v.y = f2bf(acc[im][jn][1]);
            v.z = f2bf(acc[im][jn][2]);
            v.w = f2bf(acc[im][jn][3]);
            const int c  = wc * 64 + jn * 16 + cIdx;       // tile col
            const int r  = wr * 64 + im * 16 + quad * 4;   // tile row (rg=0)
            const int r8 = r >> 3;                         // 16B-chunk index 0..15
            const int ri = r & 7;                          // 0 or 4 within chunk
            *reinterpret_cast<ushort4*>(
                &SMEM[c * 128 + ((r8 ^ (c & 15)) << 3) + ri]) = v;
        }
    __syncthreads();

    const int lch = t & 7;    // low 16B chunk of the transposed row
    const int trw = t >> 3;   // 0..31
#pragma unroll
    for (int it = 0; it < 4; ++it) {
        const int tr = it * 32 + trw;                      // transposed row = orig col
        const int q1 = lch ^ (tr & 15);
        const int q2 = (lch + 8) ^ (tr & 15);
        ushort8 a = *reinterpret_cast<const ushort8*>(&SMEM[tr * 128 + q1 * 8]);
        ushort8 b = *reinterpret_cast<const ushort8*>(&SMEM[tr * 128 + q2 * 8]);
        unsigned short* dst = simb + (size_t)(colBase + tr) * BN + rowBase;
        *reinterpret_cast<ushort8*>(&dst[lch * 8])       = a;
        *reinterpret_cast<ushort8*>(&dst[(lch + 8) * 8]) = b;
    }
}

// Per-row pass: one wave owns one full row (held in 32 VGPRs), so the row's
// min/max thresholds are wave-local -- no global atomics or threshold round
// trip. 1024 blocks x 4 waves x 1 row (max parallelism for latency hiding).
__global__ __launch_bounds__(256) void ms_rows(
    const unsigned short* __restrict__ simb,
    const int* __restrict__ labels,
    const int* __restrict__ label_num,
    float* __restrict__ out)
{
    __shared__ int   labS[BN];   // 16 KB
    __shared__ float bsum[4];

    const int t    = threadIdx.x;
    const int lane = t & 63;
    const int w    = t >> 6;

    for (int i = t; i < BN; i += 256) labS[i] = labels[i];
    __syncthreads();

    const int lim = BN - label_num[0];
    const int row = blockIdx.x * 4 + w;
    const int lr  = labS[row];
    const ushort8* rp = (const ushort8*)(simb + (size_t)row * BN);

    ushort8 d[8];
    uint64_t mpos = 0, msame = 0;
    float mn = INFINITY, mx = -INFINITY;
#pragma unroll
    for (int j = 0; j < 8; ++j) {
        d[j] = rp[j * 64 + lane];
#pragma unroll
        for (int e = 0; e < 8; ++e) {
            const int col = (j * 64 + lane) * 8 + e;
            const float s = bf2f(d[j][e]);
            const bool same = (labS[col] == lr);
            const bool pos  = same && (col != row);
            if (pos)   mn = fminf(mn, s);
            if (!same) mx = fmaxf(mx, s);
            msame |= (uint64_t)same << (j * 8 + e);
            mpos  |= (uint64_t)pos  << (j * 8 + e);
        }
    }
#pragma unroll
    for (int off = 1; off < 64; off <<= 1) {
        mn = fminf(mn, __shfl_xor(mn, off, 64));
        mx = fmaxf(mx, __shfl_xor(mx, off, 64));
    }
    const float tP = (mn < 1e30f)  ? mn : 0.2f;   // pos_thr fallback
    const float tN = (mx > -1e30f) ? mx : 0.8f;   // neg_thr fallback

    float ps = 0.f, ns = 0.f;
#pragma unroll
    for (int j = 0; j < 8; ++j)
#pragma unroll
        for (int e = 0; e < 8; ++e) {
            const int k = j * 8 + e;
            const float s = bf2f(d[j][e]);
            if (((mpos >> k) & 1) && (s - MARGIN < tN))
                ps += __expf(-2.0f * (s - THRESH));
            if (!((msame >> k) & 1) && (s + MARGIN > tP))
                ns += __expf(40.0f * (s - THRESH));
        }
#pragma unroll
    for (int off = 1; off < 64; off <<= 1) {
        ps += __shfl_xor(ps, off, 64);
        ns += __shfl_xor(ns, off, 64);
    }
    // exp terms are strictly positive -> sum>0 <=> any() of mined mask
    float wsum = 0.f;
    if (lane == 0 && ps > 0.f && ns > 0.f && row < lim)
        wsum = 0.5f * log1pf(ps) + 0.025f * log1pf(ns);

    if (lane == 0) bsum[w] = wsum;
    __syncthreads();
    if (t == 0)
        atomicAdd(out, (bsum[0] + bsum[1] + bsum[2] + bsum[3]) * (1.0f / (float)BN));
}

extern "C" void kernel_launch(void* const* d_in, const int* in_sizes, int n_in,
                              void* d_out, int out_size, void* d_ws, size_t ws_size,
                              hipStream_t stream)
{
    const float* feats     = (const float*)d_in[0];
    const int*   labels    = (const int*)d_in[1];
    const int*   label_num = (const int*)d_in[2];
    float*       out       = (float*)d_out;

    char* ws = (char*)d_ws;
    unsigned short* Fb   = (unsigned short*)ws;                        // 4 MB bf16 feats
    unsigned short* simb = (unsigned short*)(ws + 4u * 1024u * 1024u); // 32 MB bf16 sim

    cvt_kernel<<<2048, 256, 0, stream>>>((const float4*)feats, (ushort4*)Fb, out);

    ms_gemm<<<528, 256, 0, stream>>>(Fb, simb);   // upper-triangle tiles only

    ms_rows<<<1024, 256, 0, stream>>>(simb, labels, label_num, out);
}

// Round 6
// 111.939 us; speedup vs baseline: 1.3850x; 1.0027x over previous
//
#include <hip/hip_runtime.h>
#include <stdint.h>

#define BN 4096
#define DK 512
#define THRESH 0.5f
#define MARGIN 0.1f

typedef __attribute__((ext_vector_type(8))) __bf16 bf16x8;
typedef __attribute__((ext_vector_type(4))) float f32x4;
typedef __attribute__((ext_vector_type(8))) unsigned short ushort8;

__device__ __forceinline__ unsigned short f2bf(float f) {
    unsigned u = __float_as_uint(f);
    u += 0x7FFFu + ((u >> 16) & 1u);   // RNE
    return (unsigned short)(u >> 16);
}
__device__ __forceinline__ float bf2f(unsigned short b) {
    return __uint_as_float((unsigned)b << 16);
}

__device__ __forceinline__ void async_cp16(void* lds, const void* g) {
    __builtin_amdgcn_global_load_lds(
        (const __attribute__((address_space(1))) void*)g,
        (__attribute__((address_space(3))) void*)lds,
        16, 0, 0);
}

// feats fp32 -> bf16 (for MFMA); block 0 thread 0 zero-inits out[0]
// (harness re-poisons d_out to 0xAA before every timed replay).
__global__ void cvt_kernel(const float4* __restrict__ in, ushort4* __restrict__ out,
                           float* __restrict__ loss_out) {
    int i = blockIdx.x * blockDim.x + threadIdx.x;   // 524288 threads, 4 elems each
    float4 v = in[i];
    ushort4 o;
    o.x = f2bf(v.x); o.y = f2bf(v.y); o.z = f2bf(v.z); o.w = f2bf(v.w);
    out[i] = o;
    if (blockIdx.x == 0 && threadIdx.x == 0) loss_out[0] = 0.f;
}

// Triangular GEMM: sim = Fb @ Fb^T. sim is symmetric and our accumulation
// order is identical for (i,j)/(j,i), so only the 528 upper-triangle 128x128
// tiles are computed; off-diagonal blocks also store C^T (mirror) via an LDS
// round-trip reusing the 32 KB staging buffer. Diagonal tiles skip B staging
// entirely (A==B). K-loop staging keeps the round-2 XOR swizzle on the
// global-gather side (fragment reads have 128B lane stride; swizzle spreads
// a quad's 16 lanes across all 32 banks, gather stays inside one 128B seg).
__global__ __launch_bounds__(256, 4) void ms_gemm(
    const unsigned short* __restrict__ Fb,   // bf16 bits [4096][512] row-major
    unsigned short* __restrict__ simb)       // bf16 bits [4096][4096]
{
    __shared__ __align__(16) unsigned short SMEM[2 * 128 * 64];  // As|Bs, reused as 128x128 C^T
    unsigned short* As = SMEM;            // [row][k] swizzled
    unsigned short* Bs = SMEM + 128 * 64; // [col][k] swizzled

    const int t    = threadIdx.x;
    const int lane = t & 63;
    const int w    = t >> 6;
    const int wr   = w >> 1, wc = w & 1;
    const int quad = lane >> 4;
    const int cIdx = lane & 15;

    // map linear block id -> upper-triangle tile (by <= bx), 528 blocks
    int l = blockIdx.x, by = 0;
    while (l >= 32 - by) { l -= (32 - by); ++by; }
    const int bx = by + l;
    const int rowBase = by * 128;
    const int colBase = bx * 128;
    const bool diag = (by == bx);
    const unsigned short* Bsel = diag ? As : Bs;   // diagonal: A==B, skip B staging

    f32x4 acc[4][4];
#pragma unroll
    for (int i = 0; i < 4; ++i)
#pragma unroll
        for (int j = 0; j < 4; ++j) acc[i][j] = (f32x4){0.f, 0.f, 0.f, 0.f};

    const int lrow   = t >> 3;               // 0..31 (row within a 32-row staging slab)
    const int swz    = (t & 7) ^ (lrow & 7); // XOR-swizzled chunk this lane fetches
    const int ldsOff = t * 8;                // lane-contiguous LDS dest (HW requirement)

    for (int k0 = 0; k0 < DK; k0 += 64) {
#pragma unroll
        for (int it = 0; it < 4; ++it) {
            const unsigned short* gA =
                Fb + (size_t)(rowBase + it * 32 + lrow) * DK + k0 + swz * 8;
            async_cp16(&As[it * 2048 + ldsOff], gA);
        }
        if (!diag) {
#pragma unroll
            for (int it = 0; it < 4; ++it) {
                const unsigned short* gB =
                    Fb + (size_t)(colBase + it * 32 + lrow) * DK + k0 + swz * 8;
                async_cp16(&Bs[it * 2048 + ldsOff], gB);
            }
        }
        __syncthreads();   // compiler drains vmcnt before s_barrier

#pragma unroll
        for (int kk = 0; kk < 2; ++kk) {
            bf16x8 af[4], bg[4];
#pragma unroll
            for (int im = 0; im < 4; ++im) {
                int r = wr * 64 + im * 16 + cIdx;     // A[m=lane&15][k=quad*8+j]
                int p = (kk * 4 + quad) ^ (r & 7);    // de-swizzle chunk index
                af[im] = *reinterpret_cast<const bf16x8*>(&As[r * 64 + p * 8]);
            }
#pragma unroll
            for (int jn = 0; jn < 4; ++jn) {
                int c = wc * 64 + jn * 16 + cIdx;     // B[k=quad*8+j][n=lane&15]
                int p = (kk * 4 + quad) ^ (c & 7);
                bg[jn] = *reinterpret_cast<const bf16x8*>(&Bsel[c * 64 + p * 8]);
            }
#pragma unroll
            for (int im = 0; im < 4; ++im)
#pragma unroll
                for (int jn = 0; jn < 4; ++jn)
                    acc[im][jn] = __builtin_amdgcn_mfma_f32_16x16x32_bf16(
                        af[im], bg[jn], acc[im][jn], 0, 0, 0);
        }
        __syncthreads();   // last iteration: also guards SMEM reuse below
    }

    // Direct store. C/D layout (16x16): col=lane&15, row=quad*4+reg.
#pragma unroll
    for (int im = 0; im < 4; ++im)
#pragma unroll
        for (int rg = 0; rg < 4; ++rg) {
            const int grow = rowBase + wr * 64 + im * 16 + quad * 4 + rg;
            unsigned short* dst = simb + (size_t)grow * BN + colBase + wc * 64 + cIdx;
#pragma unroll
            for (int jn = 0; jn < 4; ++jn)
                dst[jn * 16] = f2bf(acc[im][jn][rg]);
        }

    if (diag) return;

    // Mirror store: write C^T into SMEM (phys 8B-chunk XOR-swizzled by column),
    // then read rows of C^T and store 16B-coalesced to sim[col][row].
#pragma unroll
    for (int im = 0; im < 4; ++im)
#pragma unroll
        for (int jn = 0; jn < 4; ++jn) {
            ushort4 v;
            v.x = f2bf(acc[im][jn][0]);
            v.y = f2bf(acc[im][jn][1]);
            v.z = f2bf(acc[im][jn][2]);
            v.w = f2bf(acc[im][jn][3]);
            const int c  = wc * 64 + jn * 16 + cIdx;       // tile col
            const int r  = wr * 64 + im * 16 + quad * 4;   // tile row (rg=0)
            const int r8 = r >> 3;                         // 16B-chunk index 0..15
            const int ri = r & 7;                          // 0 or 4 within chunk
            *reinterpret_cast<ushort4*>(
                &SMEM[c * 128 + ((r8 ^ (c & 15)) << 3) + ri]) = v;
        }
    __syncthreads();

    const int lch = t & 7;    // low 16B chunk of the transposed row
    const int trw = t >> 3;   // 0..31
#pragma unroll
    for (int it = 0; it < 4; ++it) {
        const int tr = it * 32 + trw;                      // transposed row = orig col
        const int q1 = lch ^ (tr & 15);
        const int q2 = (lch + 8) ^ (tr & 15);
        ushort8 a = *reinterpret_cast<const ushort8*>(&SMEM[tr * 128 + q1 * 8]);
        ushort8 b = *reinterpret_cast<const ushort8*>(&SMEM[tr * 128 + q2 * 8]);
        unsigned short* dst = simb + (size_t)(colBase + tr) * BN + rowBase;
        *reinterpret_cast<ushort8*>(&dst[lch * 8])       = a;
        *reinterpret_cast<ushort8*>(&dst[(lch + 8) * 8]) = b;
    }
}

// Per-row pass: one wave owns one full row (held in 32 VGPRs), so the row's
// min/max thresholds are wave-local. 1024 blocks x 4 waves x 1 row.
// Labels are staged TRANSPOSED in LDS (labT[e][col>>3]) so the per-(j,e)
// read "labels[(j*64+lane)*8+e]" becomes consecutive-word = conflict-free
// (the natural layout has lane-stride 8 words -> 16-way bank conflict).
// exp bodies are wave-ballot-guarded: pos pairs ~8/row; neg terms with
// s <= 0.125 are each < e^-15 (dropped sum <= 1.25e-3 -> Dloss <= 3.1e-5),
// so ~88% of steps skip the transcendental. Validity flags kept exact.
__global__ __launch_bounds__(256) void ms_rows(
    const unsigned short* __restrict__ simb,
    const int* __restrict__ labels,
    const int* __restrict__ label_num,
    float* __restrict__ out)
{
    __shared__ int   labT[8][512];   // 16 KB, labT[i&7][i>>3] = labels[i]
    __shared__ float bsum[4];

    const int t    = threadIdx.x;
    const int lane = t & 63;
    const int w    = t >> 6;

    for (int i = t; i < BN; i += 256) labT[i & 7][i >> 3] = labels[i];
    __syncthreads();

    const int lim = BN - label_num[0];
    const int row = blockIdx.x * 4 + w;
    const int lr  = labT[row & 7][row >> 3];
    const ushort8* rp = (const ushort8*)(simb + (size_t)row * BN);

    ushort8 d[8];
    uint64_t mpos = 0, msame = 0;
    float mn = INFINITY, mx = -INFINITY;
#pragma unroll
    for (int j = 0; j < 8; ++j) {
        d[j] = rp[j * 64 + lane];
        const int c8 = j * 64 + lane;            // col>>3 for this lane's 8 elems
#pragma unroll
        for (int e = 0; e < 8; ++e) {
            const int col = c8 * 8 + e;
            const float s = bf2f(d[j][e]);
            const bool same = (labT[e][c8] == lr);   // conflict-free LDS read
            const bool pos  = same && (col != row);
            if (pos)   mn = fminf(mn, s);
            if (!same) mx = fmaxf(mx, s);
            msame |= (uint64_t)same << (j * 8 + e);
            mpos  |= (uint64_t)pos  << (j * 8 + e);
        }
    }
#pragma unroll
    for (int off = 1; off < 64; off <<= 1) {
        mn = fminf(mn, __shfl_xor(mn, off, 64));
        mx = fmaxf(mx, __shfl_xor(mx, off, 64));
    }
    const float tP = (mn < 1e30f)  ? mn : 0.2f;   // pos_thr fallback
    const float tN = (mx > -1e30f) ? mx : 0.8f;   // neg_thr fallback

    float ps = 0.f, ns = 0.f;
    bool anyN = false;
#pragma unroll
    for (int j = 0; j < 8; ++j)
#pragma unroll
        for (int e = 0; e < 8; ++e) {
            const int k = j * 8 + e;
            const float s = bf2f(d[j][e]);
            const bool doP = ((mpos >> k) & 1) && (s - MARGIN < tN);
            if (__any(doP))
                ps += doP ? __expf(-2.0f * (s - THRESH)) : 0.f;
            const bool doN = !((msame >> k) & 1) && (s + MARGIN > tP);
            anyN |= doN;                       // exact any() for validity
            const bool doNe = doN && (s > 0.125f);   // numeric cutoff
            if (__any(doNe))
                ns += doNe ? __expf(40.0f * (s - THRESH)) : 0.f;
        }
#pragma unroll
    for (int off = 1; off < 64; off <<= 1) {
        ps += __shfl_xor(ps, off, 64);
        ns += __shfl_xor(ns, off, 64);
    }
    const bool anyNw = __any(anyN);
    // all pos terms kept -> ps>0 <=> any mined pos; neg validity via anyNw
    float wsum = 0.f;
    if (lane == 0 && ps > 0.f && anyNw && row < lim)
        wsum = 0.5f * log1pf(ps) + 0.025f * log1pf(ns);

    if (lane == 0) bsum[w] = wsum;
    __syncthreads();
    if (t == 0)
        atomicAdd(out, (bsum[0] + bsum[1] + bsum[2] + bsum[3]) * (1.0f / (float)BN));
}

extern "C" void kernel_launch(void* const* d_in, const int* in_sizes, int n_in,
                              void* d_out, int out_size, void* d_ws, size_t ws_size,
                              hipStream_t stream)
{
    const float* feats     = (const float*)d_in[0];
    const int*   labels    = (const int*)d_in[1];
    const int*   label_num = (const int*)d_in[2];
    float*       out       = (float*)d_out;

    char* ws = (char*)d_ws;
    unsigned short* Fb   = (unsigned short*)ws;                        // 4 MB bf16 feats
    unsigned short* simb = (unsigned short*)(ws + 4u * 1024u * 1024u); // 32 MB bf16 sim

    cvt_kernel<<<2048, 256, 0, stream>>>((const float4*)feats, (ushort4*)Fb, out);

    ms_gemm<<<528, 256, 0, stream>>>(Fb, simb);   // upper-triangle tiles only

    ms_rows<<<1024, 256, 0, stream>>>(simb, labels, label_num, out);
}

// Round 7
// 109.611 us; speedup vs baseline: 1.4144x; 1.0212x over previous
//
#include <hip/hip_runtime.h>
#include <stdint.h>

#define BN 4096
#define DK 512
#define THRESH 0.5f
#define MARGIN 0.1f

typedef __attribute__((ext_vector_type(4))) float f32x4;
typedef __attribute__((ext_vector_type(8))) unsigned short ushort8;

__device__ __forceinline__ unsigned short f2bf(float f) {
    unsigned u = __float_as_uint(f);
    u += 0x7FFFu + ((u >> 16) & 1u);   // RNE
    return (unsigned short)(u >> 16);
}
__device__ __forceinline__ float bf2f(unsigned short b) {
    return __uint_as_float((unsigned)b << 16);
}

// fp32 -> OCP e4m3fn, RNE (software; inputs here are |x| <~ 0.5 so the
// clamp/NaN paths are never hot). Subnormal: m = round(a * 2^9).
__device__ __forceinline__ unsigned char f2fp8(float x) {
    float a = fabsf(x);
    unsigned s = (__float_as_uint(x) >> 24) & 0x80u;
    if (a >= 448.f) return (unsigned char)(s | 0x7E);      // clamp to max finite
    if (a < 0.015625f) {                                    // < 2^-6: subnormal
        int m = (int)(a * 512.0f + 0.5f);                   // 0..8 (8 == 2^-6 normal)
        return (unsigned char)(s | m);
    }
    unsigned u = __float_as_uint(a);
    u += 0x0FFFFFu + ((u >> 20) & 1u);                      // RNE into 3-bit mantissa
    unsigned e = (u >> 23) - 127u + 7u;
    unsigned m = (u >> 20) & 7u;
    if (e >= 16u) return (unsigned char)(s | 0x7E);
    return (unsigned char)(s | (e << 3) | m);
}

__device__ __forceinline__ void async_cp16(void* lds, const void* g) {
    __builtin_amdgcn_global_load_lds(
        (const __attribute__((address_space(1))) void*)g,
        (__attribute__((address_space(3))) void*)lds,
        16, 0, 0);
}

// feats fp32 -> fp8 e4m3 (for MFMA); block 0 thread 0 zero-inits out[0]
// (harness re-poisons d_out to 0xAA before every timed replay).
__global__ void cvt_kernel(const float4* __restrict__ in, uchar4* __restrict__ out,
                           float* __restrict__ loss_out) {
    int i = blockIdx.x * blockDim.x + threadIdx.x;   // 524288 threads, 4 elems each
    float4 v = in[i];
    uchar4 o;
    o.x = f2fp8(v.x); o.y = f2fp8(v.y); o.z = f2fp8(v.z); o.w = f2fp8(v.w);
    out[i] = o;
    if (blockIdx.x == 0 && threadIdx.x == 0) loss_out[0] = 0.f;
}

// Triangular GEMM, fp8 inputs: sim = F8 @ F8^T (fp32 accumulate), bf16 store.
// Only the 528 upper-triangle 128x128 tiles are computed; off-diagonal blocks
// mirror-store C^T via an LDS round-trip. Diagonal tiles skip B staging (A==B).
//
// fp8 staging: row = 64 B per BK=64 k-slice. Fragment reads are ds_read_b64
// with 64 B lane stride; the 16B-chunk index is XOR-swizzled by (r>>1)&3 on
// the GLOBAL gather side (16B-granular, preserving global_load_lds's
// lane-contiguous LDS dest), giving 2 lanes/8B-unit = free 2-way aliasing.
__global__ __launch_bounds__(256, 4) void ms_gemm(
    const unsigned char* __restrict__ Fb,   // fp8 e4m3 [4096][512] row-major
    unsigned short* __restrict__ simb)      // bf16 bits [4096][4096]
{
    __shared__ __align__(16) unsigned char SMEMB[32768];  // 8K As | 8K Bs | mirror C^T view
    unsigned char* As = SMEMB;
    unsigned char* Bs = SMEMB + 8192;
    unsigned short* SMEM = (unsigned short*)SMEMB;        // 128x128 bf16 mirror reuse

    const int t    = threadIdx.x;
    const int lane = t & 63;
    const int w    = t >> 6;
    const int wr   = w >> 1, wc = w & 1;
    const int quad = lane >> 4;
    const int cIdx = lane & 15;

    // map linear block id -> upper-triangle tile (by <= bx), 528 blocks
    int l = blockIdx.x, by = 0;
    while (l >= 32 - by) { l -= (32 - by); ++by; }
    const int bx = by + l;
    const int rowBase = by * 128;
    const int colBase = bx * 128;
    const bool diag = (by == bx);
    const unsigned char* Bsel = diag ? As : Bs;   // diagonal: A==B, skip B staging

    f32x4 acc[4][4];
#pragma unroll
    for (int i = 0; i < 4; ++i)
#pragma unroll
        for (int j = 0; j < 4; ++j) acc[i][j] = (f32x4){0.f, 0.f, 0.f, 0.f};

    for (int k0 = 0; k0 < DK; k0 += 64) {   // k0 in elements == bytes (fp8)
#pragma unroll
        for (int it = 0; it < 2; ++it) {
            const int id = it * 256 + t;          // 0..511
            const int r  = id >> 2;               // staging row 0..127
            const int gc = (id & 3) ^ ((r >> 1) & 3);   // XOR-swizzled 16B chunk
            async_cp16(As + id * 16,
                       Fb + (size_t)(rowBase + r) * DK + k0 + gc * 16);
        }
        if (!diag) {
#pragma unroll
            for (int it = 0; it < 2; ++it) {
                const int id = it * 256 + t;
                const int r  = id >> 2;
                const int gc = (id & 3) ^ ((r >> 1) & 3);
                async_cp16(Bs + id * 16,
                           Fb + (size_t)(colBase + r) * DK + k0 + gc * 16);
            }
        }
        __syncthreads();   // compiler drains vmcnt before s_barrier

#pragma unroll
        for (int kk = 0; kk < 2; ++kk) {
            long af[4], bg[4];
#pragma unroll
            for (int im = 0; im < 4; ++im) {
                int r = wr * 64 + im * 16 + cIdx;         // A[m=lane&15][k=quad*8+j]
                int u = (kk * 4 + quad) ^ (r & 6);        // de-swizzled 8B unit
                af[im] = *reinterpret_cast<const long*>(&As[r * 64 + u * 8]);
            }
#pragma unroll
            for (int jn = 0; jn < 4; ++jn) {
                int c = wc * 64 + jn * 16 + cIdx;         // B[k=quad*8+j][n=lane&15]
                int u = (kk * 4 + quad) ^ (c & 6);
                bg[jn] = *reinterpret_cast<const long*>(&Bsel[c * 64 + u * 8]);
            }
#pragma unroll
            for (int im = 0; im < 4; ++im)
#pragma unroll
                for (int jn = 0; jn < 4; ++jn)
                    acc[im][jn] = __builtin_amdgcn_mfma_f32_16x16x32_fp8_fp8(
                        af[im], bg[jn], acc[im][jn], 0, 0, 0);
        }
        __syncthreads();   // last iteration: also guards SMEM reuse below
    }

    // Direct store. C/D layout (16x16): col=lane&15, row=quad*4+reg.
#pragma unroll
    for (int im = 0; im < 4; ++im)
#pragma unroll
        for (int rg = 0; rg < 4; ++rg) {
            const int grow = rowBase + wr * 64 + im * 16 + quad * 4 + rg;
            unsigned short* dst = simb + (size_t)grow * BN + colBase + wc * 64 + cIdx;
#pragma unroll
            for (int jn = 0; jn < 4; ++jn)
                dst[jn * 16] = f2bf(acc[im][jn][rg]);
        }

    if (diag) return;

    // Mirror store: write C^T into SMEM (phys 8B-chunk XOR-swizzled by column),
    // then read rows of C^T and store 16B-coalesced to sim[col][row].
#pragma unroll
    for (int im = 0; im < 4; ++im)
#pragma unroll
        for (int jn = 0; jn < 4; ++jn) {
            ushort4 v;
            v.x = f2bf(acc[im][jn][0]);
            v.y = f2bf(acc[im][jn][1]);
            v.z = f2bf(acc[im][jn][2]);
            v.w = f2bf(acc[im][jn][3]);
            const int c  = wc * 64 + jn * 16 + cIdx;       // tile col
            const int r  = wr * 64 + im * 16 + quad * 4;   // tile row (rg=0)
            const int r8 = r >> 3;                         // 16B-chunk index 0..15
            const int ri = r & 7;                          // 0 or 4 within chunk
            *reinterpret_cast<ushort4*>(
                &SMEM[c * 128 + ((r8 ^ (c & 15)) << 3) + ri]) = v;
        }
    __syncthreads();

    const int lch = t & 7;    // low 16B chunk of the transposed row
    const int trw = t >> 3;   // 0..31
#pragma unroll
    for (int it = 0; it < 4; ++it) {
        const int tr = it * 32 + trw;                      // transposed row = orig col
        const int q1 = lch ^ (tr & 15);
        const int q2 = (lch + 8) ^ (tr & 15);
        ushort8 a = *reinterpret_cast<const ushort8*>(&SMEM[tr * 128 + q1 * 8]);
        ushort8 b = *reinterpret_cast<const ushort8*>(&SMEM[tr * 128 + q2 * 8]);
        unsigned short* dst = simb + (size_t)(colBase + tr) * BN + rowBase;
        *reinterpret_cast<ushort8*>(&dst[lch * 8])       = a;
        *reinterpret_cast<ushort8*>(&dst[(lch + 8) * 8]) = b;
    }
}

// Per-row pass: one wave owns one full row (held in 32 VGPRs), so the row's
// min/max thresholds are wave-local. 1024 blocks x 4 waves x 1 row.
// Labels staged transposed in LDS (conflict-free per-(j,e) reads); exp bodies
// wave-ballot-guarded with an exact any() kept for validity (neg cutoff
// s <= 0.125 drops only terms < e^-15; Dloss <= 3.1e-5).
__global__ __launch_bounds__(256) void ms_rows(
    const unsigned short* __restrict__ simb,
    const int* __restrict__ labels,
    const int* __restrict__ label_num,
    float* __restrict__ out)
{
    __shared__ int   labT[8][512];   // 16 KB, labT[i&7][i>>3] = labels[i]
    __shared__ float bsum[4];

    const int t    = threadIdx.x;
    const int lane = t & 63;
    const int w    = t >> 6;

    for (int i = t; i < BN; i += 256) labT[i & 7][i >> 3] = labels[i];
    __syncthreads();

    const int lim = BN - label_num[0];
    const int row = blockIdx.x * 4 + w;
    const int lr  = labT[row & 7][row >> 3];
    const ushort8* rp = (const ushort8*)(simb + (size_t)row * BN);

    ushort8 d[8];
    uint64_t mpos = 0, msame = 0;
    float mn = INFINITY, mx = -INFINITY;
#pragma unroll
    for (int j = 0; j < 8; ++j) {
        d[j] = rp[j * 64 + lane];
        const int c8 = j * 64 + lane;            // col>>3 for this lane's 8 elems
#pragma unroll
        for (int e = 0; e < 8; ++e) {
            const int col = c8 * 8 + e;
            const float s = bf2f(d[j][e]);
            const bool same = (labT[e][c8] == lr);   // conflict-free LDS read
            const bool pos  = same && (col != row);
            if (pos)   mn = fminf(mn, s);
            if (!same) mx = fmaxf(mx, s);
            msame |= (uint64_t)same << (j * 8 + e);
            mpos  |= (uint64_t)pos  << (j * 8 + e);
        }
    }
#pragma unroll
    for (int off = 1; off < 64; off <<= 1) {
        mn = fminf(mn, __shfl_xor(mn, off, 64));
        mx = fmaxf(mx, __shfl_xor(mx, off, 64));
    }
    const float tP = (mn < 1e30f)  ? mn : 0.2f;   // pos_thr fallback
    const float tN = (mx > -1e30f) ? mx : 0.8f;   // neg_thr fallback

    float ps = 0.f, ns = 0.f;
    bool anyN = false;
#pragma unroll
    for (int j = 0; j < 8; ++j)
#pragma unroll
        for (int e = 0; e < 8; ++e) {
            const int k = j * 8 + e;
            const float s = bf2f(d[j][e]);
            const bool doP = ((mpos >> k) & 1) && (s - MARGIN < tN);
            if (__any(doP))
                ps += doP ? __expf(-2.0f * (s - THRESH)) : 0.f;
            const bool doN = !((msame >> k) & 1) && (s + MARGIN > tP);
            anyN |= doN;                       // exact any() for validity
            const bool doNe = doN && (s > 0.125f);   // numeric cutoff
            if (__any(doNe))
                ns += doNe ? __expf(40.0f * (s - THRESH)) : 0.f;
        }
#pragma unroll
    for (int off = 1; off < 64; off <<= 1) {
        ps += __shfl_xor(ps, off, 64);
        ns += __shfl_xor(ns, off, 64);
    }
    const bool anyNw = __any(anyN);
    // all pos terms kept -> ps>0 <=> any mined pos; neg validity via anyNw
    float wsum = 0.f;
    if (lane == 0 && ps > 0.f && anyNw && row < lim)
        wsum = 0.5f * log1pf(ps) + 0.025f * log1pf(ns);

    if (lane == 0) bsum[w] = wsum;
    __syncthreads();
    if (t == 0)
        atomicAdd(out, (bsum[0] + bsum[1] + bsum[2] + bsum[3]) * (1.0f / (float)BN));
}

extern "C" void kernel_launch(void* const* d_in, const int* in_sizes, int n_in,
                              void* d_out, int out_size, void* d_ws, size_t ws_size,
                              hipStream_t stream)
{
    const float* feats     = (const float*)d_in[0];
    const int*   labels    = (const int*)d_in[1];
    const int*   label_num = (const int*)d_in[2];
    float*       out       = (float*)d_out;

    char* ws = (char*)d_ws;
    unsigned char*  Fb   = (unsigned char*)ws;                         // 2 MB fp8 feats
    unsigned short* simb = (unsigned short*)(ws + 4u * 1024u * 1024u); // 32 MB bf16 sim

    cvt_kernel<<<2048, 256, 0, stream>>>((const float4*)feats, (uchar4*)Fb, out);

    ms_gemm<<<528, 256, 0, stream>>>(Fb, simb);   // upper-triangle tiles only

    ms_rows<<<1024, 256, 0, stream>>>(simb, labels, label_num, out);
}

// Round 8
// 109.303 us; speedup vs baseline: 1.4184x; 1.0028x over previous
//
#include <hip/hip_runtime.h>
#include <stdint.h>

#define BN 4096
#define DK 512
#define THRESH 0.5f
#define MARGIN 0.1f

typedef __attribute__((ext_vector_type(4))) float f32x4;
typedef __attribute__((ext_vector_type(8))) unsigned short ushort8;

__device__ __forceinline__ unsigned short f2bf(float f) {
    unsigned u = __float_as_uint(f);
    u += 0x7FFFu + ((u >> 16) & 1u);   // RNE
    return (unsigned short)(u >> 16);
}
__device__ __forceinline__ float bf2f(unsigned short b) {
    return __uint_as_float((unsigned)b << 16);
}

// fp32 -> OCP e4m3fn, RNE (software; inputs here are |x| <~ 0.5 so the
// clamp/NaN paths are never hot). Subnormal: m = round(a * 2^9).
__device__ __forceinline__ unsigned char f2fp8(float x) {
    float a = fabsf(x);
    unsigned s = (__float_as_uint(x) >> 24) & 0x80u;
    if (a >= 448.f) return (unsigned char)(s | 0x7E);      // clamp to max finite
    if (a < 0.015625f) {                                    // < 2^-6: subnormal
        int m = (int)(a * 512.0f + 0.5f);                   // 0..8 (8 == 2^-6 normal)
        return (unsigned char)(s | m);
    }
    unsigned u = __float_as_uint(a);
    u += 0x0FFFFFu + ((u >> 20) & 1u);                      // RNE into 3-bit mantissa
    unsigned e = (u >> 23) - 127u + 7u;
    unsigned m = (u >> 20) & 7u;
    if (e >= 16u) return (unsigned char)(s | 0x7E);
    return (unsigned char)(s | (e << 3) | m);
}

__device__ __forceinline__ void async_cp16(void* lds, const void* g) {
    __builtin_amdgcn_global_load_lds(
        (const __attribute__((address_space(1))) void*)g,
        (__attribute__((address_space(3))) void*)lds,
        16, 0, 0);
}

// feats fp32 -> fp8 e4m3 (for MFMA); block 0 thread 0 zero-inits out[0]
// (harness re-poisons d_out to 0xAA before every timed replay).
__global__ void cvt_kernel(const float4* __restrict__ in, uchar4* __restrict__ out,
                           float* __restrict__ loss_out) {
    int i = blockIdx.x * blockDim.x + threadIdx.x;   // 524288 threads, 4 elems each
    float4 v = in[i];
    uchar4 o;
    o.x = f2fp8(v.x); o.y = f2fp8(v.y); o.z = f2fp8(v.z); o.w = f2fp8(v.w);
    out[i] = o;
    if (blockIdx.x == 0 && threadIdx.x == 0) loss_out[0] = 0.f;
}

// Triangular GEMM, fp8 inputs: sim = F8 @ F8^T (fp32 accumulate), bf16 store.
// Only the 528 upper-triangle 128x128 tiles are computed; off-diagonal blocks
// mirror-store C^T via an LDS round-trip. Diagonal tiles skip B staging (A==B).
//
// BK=128: one K-slice = 128 B/row (16 KB per matrix, 32 KB LDS total — still
// 4 blocks/CU), so the 2-barrier K-loop runs 4 times instead of 8 -> HALF the
// all-waves-stalled vmcnt(0) barrier drains vs BK=64. Same global_load_lds
// count, same MFMA count, same k accumulation order (bit-identical sim).
// Staging swizzle: 16B chunk index XORed with (r&7) on the GLOBAL gather side
// (preserving global_load_lds's lane-contiguous LDS dest).
__global__ __launch_bounds__(256, 4) void ms_gemm(
    const unsigned char* __restrict__ Fb,   // fp8 e4m3 [4096][512] row-major
    unsigned short* __restrict__ simb)      // bf16 bits [4096][4096]
{
    __shared__ __align__(16) unsigned char SMEMB[32768];  // 16K As | 16K Bs
    unsigned char* As = SMEMB;
    unsigned char* Bs = SMEMB + 16384;
    unsigned short* SMEM = (unsigned short*)SMEMB;        // 128x128 bf16 mirror reuse

    const int t    = threadIdx.x;
    const int lane = t & 63;
    const int w    = t >> 6;
    const int wr   = w >> 1, wc = w & 1;
    const int quad = lane >> 4;
    const int cIdx = lane & 15;

    // map linear block id -> upper-triangle tile (by <= bx), 528 blocks
    int l = blockIdx.x, by = 0;
    while (l >= 32 - by) { l -= (32 - by); ++by; }
    const int bx = by + l;
    const int rowBase = by * 128;
    const int colBase = bx * 128;
    const bool diag = (by == bx);
    const unsigned char* Bsel = diag ? As : Bs;   // diagonal: A==B, skip B staging

    f32x4 acc[4][4];
#pragma unroll
    for (int i = 0; i < 4; ++i)
#pragma unroll
        for (int j = 0; j < 4; ++j) acc[i][j] = (f32x4){0.f, 0.f, 0.f, 0.f};

    for (int k0 = 0; k0 < DK; k0 += 128) {   // 4 iterations (BK=128 bytes)
#pragma unroll
        for (int it = 0; it < 4; ++it) {
            const int id = it * 256 + t;          // 0..1023
            const int r  = id >> 3;               // staging row 0..127
            const int gc = (id & 7) ^ (r & 7);    // XOR-swizzled 16B chunk
            async_cp16(As + id * 16,
                       Fb + (size_t)(rowBase + r) * DK + k0 + gc * 16);
        }
        if (!diag) {
#pragma unroll
            for (int it = 0; it < 4; ++it) {
                const int id = it * 256 + t;
                const int r  = id >> 3;
                const int gc = (id & 7) ^ (r & 7);
                async_cp16(Bs + id * 16,
                           Fb + (size_t)(colBase + r) * DK + k0 + gc * 16);
            }
        }
        __syncthreads();   // compiler drains vmcnt before s_barrier

#pragma unroll
        for (int kk = 0; kk < 4; ++kk) {
            long af[4], bg[4];
#pragma unroll
            for (int im = 0; im < 4; ++im) {
                int r = wr * 64 + im * 16 + cIdx;         // A[m=lane&15][k=quad*8+j]
                int u = kk * 4 + quad;                    // 8B k-unit 0..15
                int p = (u >> 1) ^ (r & 7);               // de-swizzled 16B chunk
                af[im] = *reinterpret_cast<const long*>(
                    &As[r * 128 + p * 16 + (u & 1) * 8]);
            }
#pragma unroll
            for (int jn = 0; jn < 4; ++jn) {
                int c = wc * 64 + jn * 16 + cIdx;         // B[k=quad*8+j][n=lane&15]
                int u = kk * 4 + quad;
                int p = (u >> 1) ^ (c & 7);
                bg[jn] = *reinterpret_cast<const long*>(
                    &Bsel[c * 128 + p * 16 + (u & 1) * 8]);
            }
#pragma unroll
            for (int im = 0; im < 4; ++im)
#pragma unroll
                for (int jn = 0; jn < 4; ++jn)
                    acc[im][jn] = __builtin_amdgcn_mfma_f32_16x16x32_fp8_fp8(
                        af[im], bg[jn], acc[im][jn], 0, 0, 0);
        }
        __syncthreads();   // last iteration: also guards SMEM reuse below
    }

    // Direct store. C/D layout (16x16): col=lane&15, row=quad*4+reg.
#pragma unroll
    for (int im = 0; im < 4; ++im)
#pragma unroll
        for (int rg = 0; rg < 4; ++rg) {
            const int grow = rowBase + wr * 64 + im * 16 + quad * 4 + rg;
            unsigned short* dst = simb + (size_t)grow * BN + colBase + wc * 64 + cIdx;
#pragma unroll
            for (int jn = 0; jn < 4; ++jn)
                dst[jn * 16] = f2bf(acc[im][jn][rg]);
        }

    if (diag) return;

    // Mirror store: write C^T into SMEM (phys 16B-chunk XOR-swizzled by column),
    // then read rows of C^T and store 16B-coalesced to sim[col][row].
#pragma unroll
    for (int im = 0; im < 4; ++im)
#pragma unroll
        for (int jn = 0; jn < 4; ++jn) {
            ushort4 v;
            v.x = f2bf(acc[im][jn][0]);
            v.y = f2bf(acc[im][jn][1]);
            v.z = f2bf(acc[im][jn][2]);
            v.w = f2bf(acc[im][jn][3]);
            const int c  = wc * 64 + jn * 16 + cIdx;       // tile col
            const int r  = wr * 64 + im * 16 + quad * 4;   // tile row (rg=0)
            const int r8 = r >> 3;                         // 16B-chunk index 0..15
            const int ri = r & 7;                          // 0 or 4 within chunk
            *reinterpret_cast<ushort4*>(
                &SMEM[c * 128 + ((r8 ^ (c & 15)) << 3) + ri]) = v;
        }
    __syncthreads();

    const int lch = t & 7;    // low 16B chunk of the transposed row
    const int trw = t >> 3;   // 0..31
#pragma unroll
    for (int it = 0; it < 4; ++it) {
        const int tr = it * 32 + trw;                      // transposed row = orig col
        const int q1 = lch ^ (tr & 15);
        const int q2 = (lch + 8) ^ (tr & 15);
        ushort8 a = *reinterpret_cast<const ushort8*>(&SMEM[tr * 128 + q1 * 8]);
        ushort8 b = *reinterpret_cast<const ushort8*>(&SMEM[tr * 128 + q2 * 8]);
        unsigned short* dst = simb + (size_t)(colBase + tr) * BN + rowBase;
        *reinterpret_cast<ushort8*>(&dst[lch * 8])       = a;
        *reinterpret_cast<ushort8*>(&dst[(lch + 8) * 8]) = b;
    }
}

// Per-row pass: one wave owns one full row (held in 32 VGPRs), so the row's
// min/max thresholds are wave-local. 1024 blocks x 4 waves x 1 row.
// Labels staged transposed in LDS (conflict-free per-(j,e) reads); exp bodies
// wave-ballot-guarded with an exact any() kept for validity (neg cutoff
// s <= 0.125 drops only terms < e^-15; Dloss <= 3.1e-5).
__global__ __launch_bounds__(256) void ms_rows(
    const unsigned short* __restrict__ simb,
    const int* __restrict__ labels,
    const int* __restrict__ label_num,
    float* __restrict__ out)
{
    __shared__ int   labT[8][512];   // 16 KB, labT[i&7][i>>3] = labels[i]
    __shared__ float bsum[4];

    const int t    = threadIdx.x;
    const int lane = t & 63;
    const int w    = t >> 6;

    for (int i = t; i < BN; i += 256) labT[i & 7][i >> 3] = labels[i];
    __syncthreads();

    const int lim = BN - label_num[0];
    const int row = blockIdx.x * 4 + w;
    const int lr  = labT[row & 7][row >> 3];
    const ushort8* rp = (const ushort8*)(simb + (size_t)row * BN);

    ushort8 d[8];
    uint64_t mpos = 0, msame = 0;
    float mn = INFINITY, mx = -INFINITY;
#pragma unroll
    for (int j = 0; j < 8; ++j) {
        d[j] = rp[j * 64 + lane];
        const int c8 = j * 64 + lane;            // col>>3 for this lane's 8 elems
#pragma unroll
        for (int e = 0; e < 8; ++e) {
            const int col = c8 * 8 + e;
            const float s = bf2f(d[j][e]);
            const bool same = (labT[e][c8] == lr);   // conflict-free LDS read
            const bool pos  = same && (col != row);
            if (pos)   mn = fminf(mn, s);
            if (!same) mx = fmaxf(mx, s);
            msame |= (uint64_t)same << (j * 8 + e);
            mpos  |= (uint64_t)pos  << (j * 8 + e);
        }
    }
#pragma unroll
    for (int off = 1; off < 64; off <<= 1) {
        mn = fminf(mn, __shfl_xor(mn, off, 64));
        mx = fmaxf(mx, __shfl_xor(mx, off, 64));
    }
    const float tP = (mn < 1e30f)  ? mn : 0.2f;   // pos_thr fallback
    const float tN = (mx > -1e30f) ? mx : 0.8f;   // neg_thr fallback

    float ps = 0.f, ns = 0.f;
    bool anyN = false;
#pragma unroll
    for (int j = 0; j < 8; ++j)
#pragma unroll
        for (int e = 0; e < 8; ++e) {
            const int k = j * 8 + e;
            const float s = bf2f(d[j][e]);
            const bool doP = ((mpos >> k) & 1) && (s - MARGIN < tN);
            if (__any(doP))
                ps += doP ? __expf(-2.0f * (s - THRESH)) : 0.f;
            const bool doN = !((msame >> k) & 1) && (s + MARGIN > tP);
            anyN |= doN;                       // exact any() for validity
            const bool doNe = doN && (s > 0.125f);   // numeric cutoff
            if (__any(doNe))
                ns += doNe ? __expf(40.0f * (s - THRESH)) : 0.f;
        }
#pragma unroll
    for (int off = 1; off < 64; off <<= 1) {
        ps += __shfl_xor(ps, off, 64);
        ns += __shfl_xor(ns, off, 64);
    }
    const bool anyNw = __any(anyN);
    // all pos terms kept -> ps>0 <=> any mined pos; neg validity via anyNw
    float wsum = 0.f;
    if (lane == 0 && ps > 0.f && anyNw && row < lim)
        wsum = 0.5f * log1pf(ps) + 0.025f * log1pf(ns);

    if (lane == 0) bsum[w] = wsum;
    __syncthreads();
    if (t == 0)
        atomicAdd(out, (bsum[0] + bsum[1] + bsum[2] + bsum[3]) * (1.0f / (float)BN));
}

extern "C" void kernel_launch(void* const* d_in, const int* in_sizes, int n_in,
                              void* d_out, int out_size, void* d_ws, size_t ws_size,
                              hipStream_t stream)
{
    const float* feats     = (const float*)d_in[0];
    const int*   labels    = (const int*)d_in[1];
    const int*   label_num = (const int*)d_in[2];
    float*       out       = (float*)d_out;

    char* ws = (char*)d_ws;
    unsigned char*  Fb   = (unsigned char*)ws;                         // 2 MB fp8 feats
    unsigned short* simb = (unsigned short*)(ws + 4u * 1024u * 1024u); // 32 MB bf16 sim

    cvt_kernel<<<2048, 256, 0, stream>>>((const float4*)feats, (uchar4*)Fb, out);

    ms_gemm<<<528, 256, 0, stream>>>(Fb, simb);   // upper-triangle tiles only

    ms_rows<<<1024, 256, 0, stream>>>(simb, labels, label_num, out);
}